// Round 3
// baseline (657.276 us; speedup 1.0000x reference)
//
#include <hip/hip_runtime.h>
#include <hip/hip_bf16.h>

// Swin-V2 window attention, fused one-block-per-window. All I/O fp32.
// B=32, H=W=64, C=60, NH=6, hd=10, WS=7 -> pad 70, nw=10, 3200 windows x 49 tok.
//
// R12: R11 structure (LDS 37.6KB -> 4 blocks/CU) + launch_bounds back to
//  (384,5). R10/R11 post-mortem: tight bounds ((384,6)) make the allocator
//  target a tiny VGPR budget and SPILL the w4/qacc arrays to scratch
//  (R11: 1.75 GB of scratch traffic = 100% of its 650us runtime). R9 proved
//  that under (384,5) the compiler instead rematerializes the weight loads
//  in-loop (cache-hot, VGPR=48, zero spill). LDS is then the occupancy
//  limiter: 37,632 B -> 4 blocks/CU = 24 waves (R9 was 3 blocks/18 waves).
//  - P2a: k/v (w4[15] nominally in regs; compiler rematerializes).
//  - P2b: q into qacc[9] (60ch x 6 token-groups), two weight-half passes.
//  - P3: scatter qacc into s_x rows ([token][h*10+d]); normalize k.
//  - P4: deferred-max online softmax (reg-light).
//  - s_q eliminated (q lives in s_x); s_v stride 10; s_k stride 12 (b128 x3).

#define WSZ 7
#define NT 49
#define CH 60
#define IMG 64
#define LOG100F 4.605170185988092f

__global__ __launch_bounds__(384, 5)
void swin_win_attn(const float* __restrict__ x,
                   const float* __restrict__ qkv_w,
                   const float* __restrict__ qkv_b,
                   const float* __restrict__ logit_scale,
                   const float* __restrict__ proj_w,
                   const float* __restrict__ proj_b,
                   float* __restrict__ out)
{
    __shared__ __align__(16) float s_x[NT * CH];      // 2940 f: x -> q -> out
    __shared__ __align__(16) float s_k[6 * NT * 12];  // 3528 f, 48B rows (b128 x3)
    __shared__ __align__(16) float s_v[6 * NT * 10];  // 2940 f, 40B rows (b64 x5)
    // total 9408 floats = 37,632 B -> 4 blocks/CU = 24 waves

    const int tid  = threadIdx.x;
    const int lane = tid & 63;
    const int wv   = __builtin_amdgcn_readfirstlane(tid >> 6);
    const int w  = blockIdx.x;
    const int b  = w / 100;
    const int wy = (w / 10) % 10;
    const int wx = w % 10;
    const int row0 = wy * WSZ;
    const int col0 = wx * WSZ;

    // ---- Phase 1: stage x tile (49x60, rows 240B) + zero k pad words ----
    for (int idx = tid; idx < NT * 15; idx += 384) {
        int t = idx / 15, m = idx - t * 15;
        int r  = row0 + t / WSZ;
        int cc = col0 + t % WSZ;
        float4 v4 = make_float4(0.f, 0.f, 0.f, 0.f);
        if (r < IMG && cc < IMG)
            v4 = reinterpret_cast<const float4*>(x + ((b * IMG + r) * IMG + cc) * CH)[m];
        *reinterpret_cast<float4*>(s_x + t * CH + 4 * m) = v4;
    }
    if (tid < 6 * NT) {                 // k pad lanes (d=10,11) zeroed once
        s_k[tid * 12 + 10] = 0.f;
        s_k[tid * 12 + 11] = 0.f;
    }
    __syncthreads();

    // ---- Phase 2a: k/v. thread = (kv channel c120<120, token-third).
    //      w4[15] is the only big live set in this region. ----
    float qacc[9];                      // filled in P2b, scattered in P3
    if (tid < 360) {
        const int c120  = tid % 120;
        const int third = tid / 120;
        const int isv = (c120 >= 60) ? 1 : 0;
        const int cl  = c120 - 60 * isv;
        const int c   = 60 + 60 * isv + cl;          // 60..119 = k, 120..179 = v
        const int h = cl / 10, d = cl - 10 * (cl / 10);
        const float bias = qkv_b[c];
        const float4* wp = reinterpret_cast<const float4*>(qkv_w + c * CH);
        float4 w4[15];
        #pragma unroll
        for (int m = 0; m < 15; ++m) w4[m] = wp[m];
        float* dst = isv ? (s_v + (h * NT) * 10 + d) : (s_k + (h * NT) * 12 + d);
        const int stride = isv ? 10 : 12;
        const int t0 = third * 16;
        const int t1 = (third == 2) ? NT : t0 + 16;
        for (int t = t0; t < t1; ++t) {
            float a = bias;
            const float4* xr = reinterpret_cast<const float4*>(s_x + t * CH);
            #pragma unroll
            for (int m = 0; m < 15; ++m) {
                float4 xv = xr[m];       // broadcast (<=2 addrs per wave)
                a += xv.x * w4[m].x + xv.y * w4[m].y + xv.z * w4[m].z + xv.w * w4[m].w;
            }
            dst[t * stride] = a;
        }
    }

    // ---- Phase 2b: q into qacc[9]. thread = (q channel qc<60, group qg<6).
    //      Two weight-half passes keep the live set small. ----
    {
        const int qc = tid % 60;
        const int qg = tid / 60;
        if (tid < 360) {
            const int cnt = (qg == 5) ? 9 : 8;
            const int t0 = qg * 8;
            const float bias = qkv_b[qc];
            const float4* wp = reinterpret_cast<const float4*>(qkv_w + qc * CH);
            #pragma unroll
            for (int tt = 0; tt < 9; ++tt) qacc[tt] = bias;
            {
                float4 w4[8];
                #pragma unroll
                for (int m = 0; m < 8; ++m) w4[m] = wp[m];
                #pragma unroll
                for (int tt = 0; tt < 9; ++tt) {
                    if (tt < cnt) {
                        const float4* xr = reinterpret_cast<const float4*>(s_x + (t0 + tt) * CH);
                        float a = 0.f;
                        #pragma unroll
                        for (int m = 0; m < 8; ++m) {
                            float4 xv = xr[m];
                            a += xv.x * w4[m].x + xv.y * w4[m].y + xv.z * w4[m].z + xv.w * w4[m].w;
                        }
                        qacc[tt] += a;
                    }
                }
            }
            {
                float4 w4[7];
                #pragma unroll
                for (int m = 0; m < 7; ++m) w4[m] = wp[8 + m];
                #pragma unroll
                for (int tt = 0; tt < 9; ++tt) {
                    if (tt < cnt) {
                        const float4* xr = reinterpret_cast<const float4*>(s_x + (t0 + tt) * CH) + 8;
                        float a = 0.f;
                        #pragma unroll
                        for (int m = 0; m < 7; ++m) {
                            float4 xv = xr[m];
                            a += xv.x * w4[m].x + xv.y * w4[m].y + xv.z * w4[m].z + xv.w * w4[m].w;
                        }
                        qacc[tt] += a;
                    }
                }
            }
        }
    }
    __syncthreads();

    // ---- Phase 3: scatter q into s_x rows ([t][h*10+d]); normalize k rows ----
    if (tid < 360) {
        const int qc = tid % 60;
        const int qg = tid / 60;
        const int cnt = (qg == 5) ? 9 : 8;
        const int t0 = qg * 8;
        #pragma unroll
        for (int tt = 0; tt < 9; ++tt)
            if (tt < cnt) s_x[(t0 + tt) * CH + qc] = qacc[tt];
    }
    if (tid < 6 * NT) {
        float* p = s_k + tid * 12;
        float ss = 0.f;
        #pragma unroll
        for (int d = 0; d < 10; ++d) ss += p[d] * p[d];
        float inv = 1.f / fmaxf(sqrtf(ss), 1e-12f);
        #pragma unroll
        for (int d = 0; d < 10; ++d) p[d] *= inv;
    }
    __syncthreads();

    // ---- Phase 4: attention; thread = (head,row); deferred-max online softmax ----
    if (tid < 6 * NT) {
        const int h = tid / NT, i = tid - h * NT;
        float scale = __expf(fminf(logit_scale[h], LOG100F));
        float q[10];
        {
            const float2* qp = reinterpret_cast<const float2*>(s_x + i * CH + h * 10);
            #pragma unroll
            for (int d2 = 0; d2 < 5; ++d2) { float2 t2 = qp[d2]; q[2*d2] = t2.x; q[2*d2+1] = t2.y; }
            float ss = 0.f;
            #pragma unroll
            for (int d = 0; d < 10; ++d) ss += q[d] * q[d];
            float inv = scale / fmaxf(sqrtf(ss), 1e-12f);  // fold scale into q
            #pragma unroll
            for (int d = 0; d < 10; ++d) q[d] *= inv;
        }
        float m = -1e30f, s = 0.f;
        float o[10];
        #pragma unroll
        for (int d = 0; d < 10; ++d) o[d] = 0.f;
        const float4* kb = reinterpret_cast<const float4*>(s_k + h * NT * 12);
        const float2* vb = reinterpret_cast<const float2*>(s_v + h * NT * 10);
        for (int j = 0; j < NT; ++j) {
            float4 k0 = kb[j * 3 + 0];
            float4 k1 = kb[j * 3 + 1];
            float4 k2 = kb[j * 3 + 2];   // .z,.w zeroed pads
            float a = q[0]*k0.x + q[1]*k0.y + q[2]*k0.z + q[3]*k0.w
                    + q[4]*k1.x + q[5]*k1.y + q[6]*k1.z + q[7]*k1.w
                    + q[8]*k2.x + q[9]*k2.y;
            if (a > m + 8.f) {           // rare: rescale running state
                float r = __expf(m - a);
                s *= r;
                #pragma unroll
                for (int d = 0; d < 10; ++d) o[d] *= r;
                m = a;
            }
            float p = __expf(a - m);     // bounded by e^8
            s += p;
            float2 v0 = vb[j * 5 + 0], v1 = vb[j * 5 + 1], v2 = vb[j * 5 + 2],
                   v3 = vb[j * 5 + 3], v4 = vb[j * 5 + 4];
            o[0] += p * v0.x; o[1] += p * v0.y; o[2] += p * v1.x; o[3] += p * v1.y;
            o[4] += p * v2.x; o[5] += p * v2.y; o[6] += p * v3.x; o[7] += p * v3.y;
            o[8] += p * v4.x; o[9] += p * v4.y;
        }
        float invs = 1.f / s;
        float* op = s_x + i * CH + h * 10;   // overwrite own q slots only
        #pragma unroll
        for (int d2 = 0; d2 < 5; ++d2)
            *reinterpret_cast<float2*>(op + 2 * d2) =
                make_float2(o[2*d2] * invs, o[2*d2+1] * invs);
    }
    __syncthreads();

    // ---- Phase 5: proj. lane<60 = out channel, W-row in regs, tokens over 6 waves ----
    if (lane < 60) {
        float4 w4[15];
        const float4* wp = reinterpret_cast<const float4*>(proj_w + lane * CH);
        #pragma unroll
        for (int m = 0; m < 15; ++m) w4[m] = wp[m];
        const float bias = proj_b[lane];
        for (int t = wv; t < NT; t += 6) {
            int r  = row0 + t / WSZ;
            int cc = col0 + t % WSZ;
            float a = bias;
            const float4* xr = reinterpret_cast<const float4*>(s_x + t * CH);
            #pragma unroll
            for (int m = 0; m < 15; ++m) {
                float4 xv = xr[m];                    // broadcast
                a += xv.x * w4[m].x + xv.y * w4[m].y
                   + xv.z * w4[m].z + xv.w * w4[m].w;
            }
            if (r < IMG && cc < IMG)
                out[((b * IMG + r) * IMG + cc) * CH + lane] = a;   // coalesced
        }
    }
}

extern "C" void kernel_launch(void* const* d_in, const int* in_sizes, int n_in,
                              void* d_out, int out_size, void* d_ws, size_t ws_size,
                              hipStream_t stream) {
    hipLaunchKernelGGL(swin_win_attn, dim3(3200), dim3(384), 0, stream,
                       (const float*)d_in[0], (const float*)d_in[1],
                       (const float*)d_in[2], (const float*)d_in[3],
                       (const float*)d_in[4], (const float*)d_in[5],
                       (float*)d_out);
}

// Round 5
// 436.967 us; speedup vs baseline: 1.5042x; 1.5042x over previous
//
#include <hip/hip_runtime.h>

// Swin-V2 window attention, fused one-block-per-window. All I/O fp32.
// B=32, H=W=64, C=60, NH=6, hd=10, WS=7 -> pad 70, nw=10, 3200 windows x 49 tok.
//
// R14 = R13 resubmitted verbatim (R13's bench died to a container/infra
// failure before running; no kernel evidence against it).
//
// R13: 4 blocks/CU (LDS 39,984 B) with pure fp32 and R9's proven code shapes.
//  R10-R12 post-mortem: ANY register array held across a barrier sends the
//  whole function to scratch (R12: 1.5 GB scratch traffic). So instead:
//  - s_x eliminated: P2 reads x rows straight from GLOBAL. All lanes of a
//    wave read the same float4 (broadcast, one cacheline, L1-hot; 11.8 KB
//    per block, windows disjoint => HBM traffic unchanged). P1 staging gone.
//    Pad tokens skip the dot entirely (a = bias), matching zero-padded ref.
//  - out-buffer eliminated: P4 thread (h,i) reads q from s_q[tid*10] (its
//    own slots) and writes its output back to the SAME slots (thread-private,
//    race-free). P5 gathers o in [h][t][d] layout (float2 x5 per head,
//    wave-uniform broadcast reads).
//  - k,v stride 12 (48B rows, b128 x3 reads, pads zeroed); q stride 10.
//  - P4: deferred-max online softmax (validated R10-R12, reg-light).
//  - No register state crosses any barrier. launch_bounds(384,5) as in R9.

#define WSZ 7
#define NT 49
#define CH 60
#define IMG 64
#define LOG100F 4.605170185988092f

__global__ __launch_bounds__(384, 5)
void swin_win_attn(const float* __restrict__ x,
                   const float* __restrict__ qkv_w,
                   const float* __restrict__ qkv_b,
                   const float* __restrict__ logit_scale,
                   const float* __restrict__ proj_w,
                   const float* __restrict__ proj_b,
                   float* __restrict__ out)
{
    __shared__ __align__(16) float s_q[6 * NT * 10];  // 2940 f; q then attn-out
    __shared__ __align__(16) float s_k[6 * NT * 12];  // 3528 f, 48B rows
    __shared__ __align__(16) float s_v[6 * NT * 12];  // 3528 f => 39,984 B total

    const int tid  = threadIdx.x;
    const int lane = tid & 63;
    const int wv   = __builtin_amdgcn_readfirstlane(tid >> 6);
    const int w  = blockIdx.x;
    const int b  = w / 100;
    const int wy = (w / 10) % 10;
    const int wx = w % 10;
    const int row0 = wy * WSZ;
    const int col0 = wx * WSZ;

    // ---- Phase 2 (fused pad-zero + qkv from global x) ----
    if (tid < 6 * NT) {                 // zero k/v pad words (d=10,11)
        s_k[tid * 12 + 10] = 0.f;
        s_k[tid * 12 + 11] = 0.f;
        s_v[tid * 12 + 10] = 0.f;
        s_v[tid * 12 + 11] = 0.f;
    }
    if (tid < 360) {
        const int c    = tid % 180;
        const int half = tid / 180;
        const int part = c / 60;
        const int cl   = c - 60 * part;
        const int h = cl / 10, d = cl - 10 * (cl / 10);
        float4 w4[15];
        const float4* wp = reinterpret_cast<const float4*>(qkv_w + c * CH);
        #pragma unroll
        for (int m = 0; m < 15; ++m) w4[m] = wp[m];
        const float bias = qkv_b[c];
        const int t0 = half ? 25 : 0, t1 = half ? NT : 25;
        for (int t = t0; t < t1; ++t) {
            const int tr = t / WSZ, tc = t - WSZ * tr;
            float a = bias;
            if (row0 + tr < IMG && col0 + tc < IMG) {
                const float4* xr = reinterpret_cast<const float4*>(
                    x + ((b * IMG + row0 + tr) * IMG + col0 + tc) * CH);
                #pragma unroll
                for (int m = 0; m < 15; ++m) {
                    float4 xv = xr[m];   // wave-uniform broadcast, L1-hot
                    a += xv.x * w4[m].x + xv.y * w4[m].y + xv.z * w4[m].z + xv.w * w4[m].w;
                }
            }
            if (part == 0)      s_q[(h * NT + t) * 10 + d] = a;
            else if (part == 1) s_k[(h * NT + t) * 12 + d] = a;
            else                s_v[(h * NT + t) * 12 + d] = a;
        }
    }
    __syncthreads();

    // ---- Phase 3: L2-normalize k rows (q normalized inside P4) ----
    if (tid < 6 * NT) {
        float* p = s_k + tid * 12;
        float ss = 0.f;
        #pragma unroll
        for (int d = 0; d < 10; ++d) ss += p[d] * p[d];
        float inv = 1.f / fmaxf(sqrtf(ss), 1e-12f);
        #pragma unroll
        for (int d = 0; d < 10; ++d) p[d] *= inv;
    }
    __syncthreads();

    // ---- Phase 4: attention; thread = (head,row); deferred-max online softmax.
    //      q read from own s_q slots; output written back to the SAME slots. ----
    if (tid < 6 * NT) {
        const int h = tid / NT;
        float scale = __expf(fminf(logit_scale[h], LOG100F));
        float q[10];
        {
            const float2* qp = reinterpret_cast<const float2*>(s_q + tid * 10);
            #pragma unroll
            for (int d2 = 0; d2 < 5; ++d2) { float2 t2 = qp[d2]; q[2*d2] = t2.x; q[2*d2+1] = t2.y; }
            float ss = 0.f;
            #pragma unroll
            for (int d = 0; d < 10; ++d) ss += q[d] * q[d];
            float inv = scale / fmaxf(sqrtf(ss), 1e-12f);  // fold scale into q
            #pragma unroll
            for (int d = 0; d < 10; ++d) q[d] *= inv;
        }
        float m = -1e30f, s = 0.f;
        float o[10];
        #pragma unroll
        for (int d = 0; d < 10; ++d) o[d] = 0.f;
        const float4* kb = reinterpret_cast<const float4*>(s_k + h * NT * 12);
        const float4* vb = reinterpret_cast<const float4*>(s_v + h * NT * 12);
        for (int j = 0; j < NT; ++j) {
            float4 k0 = kb[j * 3 + 0];
            float4 k1 = kb[j * 3 + 1];
            float4 k2 = kb[j * 3 + 2];   // .z,.w zeroed pads
            float a = q[0]*k0.x + q[1]*k0.y + q[2]*k0.z + q[3]*k0.w
                    + q[4]*k1.x + q[5]*k1.y + q[6]*k1.z + q[7]*k1.w
                    + q[8]*k2.x + q[9]*k2.y;
            if (a > m + 8.f) {           // rare: rescale running state
                float r = __expf(m - a);
                s *= r;
                #pragma unroll
                for (int d = 0; d < 10; ++d) o[d] *= r;
                m = a;
            }
            float p = __expf(a - m);     // bounded by e^8
            s += p;
            float4 v0 = vb[j * 3 + 0];
            float4 v1 = vb[j * 3 + 1];
            float4 v2 = vb[j * 3 + 2];
            o[0] += p * v0.x; o[1] += p * v0.y; o[2] += p * v0.z; o[3] += p * v0.w;
            o[4] += p * v1.x; o[5] += p * v1.y; o[6] += p * v1.z; o[7] += p * v1.w;
            o[8] += p * v2.x; o[9] += p * v2.y;
        }
        float invs = 1.f / s;
        float* op = s_q + tid * 10;      // overwrite own q slots only
        #pragma unroll
        for (int d2 = 0; d2 < 5; ++d2)
            *reinterpret_cast<float2*>(op + 2 * d2) =
                make_float2(o[2*d2] * invs, o[2*d2+1] * invs);
    }
    __syncthreads();

    // ---- Phase 5: proj. lane<60 = out channel; o gathered from s_q [h][t][d] ----
    if (lane < 60) {
        float wr[60];
        const float4* wp = reinterpret_cast<const float4*>(proj_w + lane * CH);
        #pragma unroll
        for (int m = 0; m < 15; ++m) {
            float4 t4 = wp[m];
            wr[4*m+0] = t4.x; wr[4*m+1] = t4.y; wr[4*m+2] = t4.z; wr[4*m+3] = t4.w;
        }
        const float bias = proj_b[lane];
        for (int t = wv; t < NT; t += 6) {
            const int tr = t / WSZ, tc = t - WSZ * tr;
            const int r  = row0 + tr;
            const int cc = col0 + tc;
            if (r < IMG && cc < IMG) {
                float a = bias;
                #pragma unroll
                for (int h2 = 0; h2 < 6; ++h2) {
                    const float2* orow = reinterpret_cast<const float2*>(s_q + (h2 * NT + t) * 10);
                    #pragma unroll
                    for (int m2 = 0; m2 < 5; ++m2) {
                        float2 ov = orow[m2];        // broadcast
                        a += ov.x * wr[h2 * 10 + 2 * m2]
                           + ov.y * wr[h2 * 10 + 2 * m2 + 1];
                    }
                }
                out[((b * IMG + r) * IMG + cc) * CH + lane] = a;   // coalesced
            }
        }
    }
}

extern "C" void kernel_launch(void* const* d_in, const int* in_sizes, int n_in,
                              void* d_out, int out_size, void* d_ws, size_t ws_size,
                              hipStream_t stream) {
    hipLaunchKernelGGL(swin_win_attn, dim3(3200), dim3(384), 0, stream,
                       (const float*)d_in[0], (const float*)d_in[1],
                       (const float*)d_in[2], (const float*)d_in[3],
                       (const float*)d_in[4], (const float*)d_in[5],
                       (float*)d_out);
}

// Round 6
// 317.255 us; speedup vs baseline: 2.0718x; 1.3773x over previous
//
#include <hip/hip_runtime.h>

// Swin-V2 window attention, fused one-block-per-window. All I/O fp32.
// B=32, H=W=64, C=60, NH=6, hd=10, WS=7 -> pad 70, nw=10, 3200 windows x 49 tok.
//
// R15: revert to R9 structure (s_x LDS staging; 51.7KB, 3 blocks/CU) after
//  R14 proved (a) occupancy is NOT the limiter (4 blocks/CU -> same 30%
//  measured, 2x slower) and (b) x must be staged in LDS: with VGPR=48 the
//  compiler rematerializes w4[15] from L1 in-loop, so global-x made P2 issue
//  30 global loads/token (VALUBusy 61->39%). Grafted R14 wins kept:
//  - P4: deferred-max ONLINE softmax -> a[49] array deleted (R9 kept it in
//    AGPRs; ~100 v_accvgpr moves + max-pass + exp-pass removed from P4).
//  - Wave-uniform pad-token skips in P2/P5 (t is lane-invariant -> free).
//  Everything else byte-for-byte R9: P1 coalesced stage + k/v pad zeroing,
//  P2 thread=(c,half) LDS-broadcast dots, P3 k-normalize, P4 out -> s_x
//  alias [t][c], P5 contiguous b128 row reads, coalesced stores.

#define WSZ 7
#define NT 49
#define CH 60
#define IMG 64
#define LOG100F 4.605170185988092f

__global__ __launch_bounds__(384, 5)
void swin_win_attn(const float* __restrict__ x,
                   const float* __restrict__ qkv_w,
                   const float* __restrict__ qkv_b,
                   const float* __restrict__ logit_scale,
                   const float* __restrict__ proj_w,
                   const float* __restrict__ proj_b,
                   float* __restrict__ out)
{
    __shared__ __align__(16) float s_x[NT * CH];      // 2940 f; aliased as s_out after P2
    __shared__ __align__(16) float s_q[6 * NT * 10];  // 2940 f, stride-10 rows
    __shared__ __align__(16) float s_k[6 * NT * 12];  // 3528 f, 48B rows (b128 x3)
    __shared__ __align__(16) float s_v[6 * NT * 12];  // 3528 f  => 51,744 B total

    const int tid  = threadIdx.x;
    const int lane = tid & 63;
    const int wv   = __builtin_amdgcn_readfirstlane(tid >> 6);
    const int w  = blockIdx.x;
    const int b  = w / 100;
    const int wy = (w / 10) % 10;
    const int wx = w % 10;
    const int row0 = wy * WSZ;
    const int col0 = wx * WSZ;

    // ---- Phase 1: stage x tile (49x60, rows 240B) + zero k/v pad words ----
    for (int idx = tid; idx < NT * 15; idx += 384) {
        int t = idx / 15, m = idx - t * 15;
        int r  = row0 + t / WSZ;
        int cc = col0 + t % WSZ;
        float4 v4 = make_float4(0.f, 0.f, 0.f, 0.f);
        if (r < IMG && cc < IMG)
            v4 = reinterpret_cast<const float4*>(x + ((b * IMG + r) * IMG + cc) * CH)[m];
        *reinterpret_cast<float4*>(s_x + t * CH + 4 * m) = v4;
    }
    for (int idx = tid; idx < 2 * 6 * NT; idx += 384) {  // 588 pad pairs
        int r = idx >> 1, p = idx & 1;
        s_k[r * 12 + 10 + p] = 0.f;
        s_v[r * 12 + 10 + p] = 0.f;
    }
    __syncthreads();

    // ---- Phase 2: qkv. thread = (channel, token-half); 360 slots of 384.
    //      One 60-float weight row (rematerialized L1-hot); x via LDS b128
    //      broadcast. Pad tokens skip the dot (wave-uniform branch). ----
    if (tid < 360) {
        const int c    = tid % 180;
        const int half = tid / 180;
        const int part = c / 60;
        const int cl   = c - 60 * part;
        const int h = cl / 10, d = cl - 10 * (cl / 10);
        float4 w4[15];
        const float4* wp = reinterpret_cast<const float4*>(qkv_w + c * CH);
        #pragma unroll
        for (int m = 0; m < 15; ++m) w4[m] = wp[m];
        const float bias = qkv_b[c];
        const int t0 = half ? 25 : 0, t1 = half ? NT : 25;
        for (int t = t0; t < t1; ++t) {
            const int tr = t / WSZ, tc = t - WSZ * tr;
            float a = bias;
            if (row0 + tr < IMG && col0 + tc < IMG) {   // wave-uniform skip
                const float4* xr = reinterpret_cast<const float4*>(s_x + t * CH);
                #pragma unroll
                for (int m = 0; m < 15; ++m) {
                    float4 xv = xr[m];               // broadcast (<=2 addrs per wave)
                    a += xv.x * w4[m].x + xv.y * w4[m].y + xv.z * w4[m].z + xv.w * w4[m].w;
                }
            }
            if (part == 0)      s_q[(h * NT + t) * 10 + d] = a;
            else if (part == 1) s_k[(h * NT + t) * 12 + d] = a;
            else                s_v[(h * NT + t) * 12 + d] = a;
        }
    }
    __syncthreads();

    // ---- Phase 3: L2-normalize k rows only (q normalized inside P4) ----
    if (tid < 6 * NT) {
        float* p = s_k + tid * 12;
        float ss = 0.f;
        #pragma unroll
        for (int d = 0; d < 10; ++d) ss += p[d] * p[d];
        float inv = 1.f / fmaxf(sqrtf(ss), 1e-12f);
        #pragma unroll
        for (int d = 0; d < 10; ++d) p[d] *= inv;
    }
    __syncthreads();

    // ---- Phase 4: attention; thread = (head,row); deferred-max ONLINE softmax ----
    if (tid < 6 * NT) {
        const int h = tid / NT, i = tid - h * NT;
        float scale = __expf(fminf(logit_scale[h], LOG100F));
        float q[10];
        {
            const float2* qp = reinterpret_cast<const float2*>(s_q + tid * 10);
            #pragma unroll
            for (int d2 = 0; d2 < 5; ++d2) { float2 t2 = qp[d2]; q[2*d2] = t2.x; q[2*d2+1] = t2.y; }
            float ss = 0.f;
            #pragma unroll
            for (int d = 0; d < 10; ++d) ss += q[d] * q[d];
            float inv = scale / fmaxf(sqrtf(ss), 1e-12f);  // fold scale into q
            #pragma unroll
            for (int d = 0; d < 10; ++d) q[d] *= inv;
        }
        float m = -1e30f, s = 0.f;
        float o[10];
        #pragma unroll
        for (int d = 0; d < 10; ++d) o[d] = 0.f;
        const float4* kb = reinterpret_cast<const float4*>(s_k + h * NT * 12);
        const float4* vb = reinterpret_cast<const float4*>(s_v + h * NT * 12);
        for (int j = 0; j < NT; ++j) {
            float4 k0 = kb[j * 3 + 0];
            float4 k1 = kb[j * 3 + 1];
            float4 k2 = kb[j * 3 + 2];   // .z,.w zeroed pads
            float a = q[0]*k0.x + q[1]*k0.y + q[2]*k0.z + q[3]*k0.w
                    + q[4]*k1.x + q[5]*k1.y + q[6]*k1.z + q[7]*k1.w
                    + q[8]*k2.x + q[9]*k2.y;
            if (a > m + 8.f) {           // rare: rescale running state
                float r = __expf(m - a);
                s *= r;
                #pragma unroll
                for (int d = 0; d < 10; ++d) o[d] *= r;
                m = a;
            }
            float p = __expf(a - m);     // bounded by e^8
            s += p;
            float4 v0 = vb[j * 3 + 0];
            float4 v1 = vb[j * 3 + 1];
            float4 v2 = vb[j * 3 + 2];
            o[0] += p * v0.x; o[1] += p * v0.y; o[2] += p * v0.z; o[3] += p * v0.w;
            o[4] += p * v1.x; o[5] += p * v1.y; o[6] += p * v1.z; o[7] += p * v1.w;
            o[8] += p * v2.x; o[9] += p * v2.y;
        }
        float invs = 1.f / s;
        float* op = s_x + i * CH + h * 10;   // s_out aliases s_x
        #pragma unroll
        for (int d2 = 0; d2 < 5; ++d2)
            *reinterpret_cast<float2*>(op + 2 * d2) =
                make_float2(o[2*d2] * invs, o[2*d2+1] * invs);
    }
    __syncthreads();

    // ---- Phase 5: proj. lane<60 = out channel, W-row in regs, tokens over 6 waves ----
    if (lane < 60) {
        float4 w4[15];
        const float4* wp = reinterpret_cast<const float4*>(proj_w + lane * CH);
        #pragma unroll
        for (int m = 0; m < 15; ++m) w4[m] = wp[m];
        const float bias = proj_b[lane];
        for (int t = wv; t < NT; t += 6) {
            int r  = row0 + t / WSZ;
            int cc = col0 + t % WSZ;
            if (r < IMG && cc < IMG) {          // wave-uniform skip
                float a = bias;
                const float4* xr = reinterpret_cast<const float4*>(s_x + t * CH);
                #pragma unroll
                for (int m = 0; m < 15; ++m) {
                    float4 xv = xr[m];                    // broadcast
                    a += xv.x * w4[m].x + xv.y * w4[m].y
                       + xv.z * w4[m].z + xv.w * w4[m].w;
                }
                out[((b * IMG + r) * IMG + cc) * CH + lane] = a;   // coalesced
            }
        }
    }
}

extern "C" void kernel_launch(void* const* d_in, const int* in_sizes, int n_in,
                              void* d_out, int out_size, void* d_ws, size_t ws_size,
                              hipStream_t stream) {
    hipLaunchKernelGGL(swin_win_attn, dim3(3200), dim3(384), 0, stream,
                       (const float*)d_in[0], (const float*)d_in[1],
                       (const float*)d_in[2], (const float*)d_in[3],
                       (const float*)d_in[4], (const float*)d_in[5],
                       (float*)d_out);
}

// Round 7
// 316.172 us; speedup vs baseline: 2.0789x; 1.0034x over previous
//
#include <hip/hip_runtime.h>

// Swin-V2 window attention, fused one-block-per-window. All I/O fp32.
// B=32, H=W=64, C=60, NH=6, hd=10, WS=7 -> pad 70, nw=10, 3200 windows x 49 tok.
//
// R16: R9 structure + ILP fixes. R15 post-mortem: online softmax's per-j
//  branch serialized P4 (213->277us) -- reverted to R9's two-pass a[49]
//  (AGPR-resident, ILP-rich). The real stall source: 60-FMA single-
//  accumulator chains in P2/P5 (chain depth 60 x ~4cyc, only ~4.5 waves/SIMD
//  to hide). Changes vs R9:
//  - P2/P5 dots: 4 independent accumulators (per float4 component) ->
//    chain depth 15. P3: 2 accums. P4 QK dot: 2 accums (even/odd d).
//  - P4 max pass: 4-way partial-max tree (unrolled, static idx -> AGPRs).
//  - Wave-uniform pad-token skips in P2/P5 kept (edge windows skip 42/49
//    dots; exculpated in R15 analysis).
//  Everything else byte-for-byte R9: P1 stage+pad-zero, P2 (c,half) map,
//  LDS b128 broadcasts, P3 k-norm, P4 out->s_x alias, P5 coalesced stores.

#define WSZ 7
#define NT 49
#define CH 60
#define IMG 64
#define LOG100F 4.605170185988092f

__global__ __launch_bounds__(384, 5)
void swin_win_attn(const float* __restrict__ x,
                   const float* __restrict__ qkv_w,
                   const float* __restrict__ qkv_b,
                   const float* __restrict__ logit_scale,
                   const float* __restrict__ proj_w,
                   const float* __restrict__ proj_b,
                   float* __restrict__ out)
{
    __shared__ __align__(16) float s_x[NT * CH];      // 2940 f; aliased as s_out after P2
    __shared__ __align__(16) float s_q[6 * NT * 10];  // 2940 f, stride-10 rows
    __shared__ __align__(16) float s_k[6 * NT * 12];  // 3528 f, 48B rows (b128 x3)
    __shared__ __align__(16) float s_v[6 * NT * 12];  // 3528 f  => 51,744 B total

    const int tid  = threadIdx.x;
    const int lane = tid & 63;
    const int wv   = __builtin_amdgcn_readfirstlane(tid >> 6);
    const int w  = blockIdx.x;
    const int b  = w / 100;
    const int wy = (w / 10) % 10;
    const int wx = w % 10;
    const int row0 = wy * WSZ;
    const int col0 = wx * WSZ;

    // ---- Phase 1: stage x tile (49x60, rows 240B) + zero k/v pad words ----
    for (int idx = tid; idx < NT * 15; idx += 384) {
        int t = idx / 15, m = idx - t * 15;
        int r  = row0 + t / WSZ;
        int cc = col0 + t % WSZ;
        float4 v4 = make_float4(0.f, 0.f, 0.f, 0.f);
        if (r < IMG && cc < IMG)
            v4 = reinterpret_cast<const float4*>(x + ((b * IMG + r) * IMG + cc) * CH)[m];
        *reinterpret_cast<float4*>(s_x + t * CH + 4 * m) = v4;
    }
    for (int idx = tid; idx < 2 * 6 * NT; idx += 384) {  // 588 pad pairs
        int r = idx >> 1, p = idx & 1;
        s_k[r * 12 + 10 + p] = 0.f;
        s_v[r * 12 + 10 + p] = 0.f;
    }
    __syncthreads();

    // ---- Phase 2: qkv. thread = (channel, token-half); 360 slots of 384.
    //      4 accumulators (per float4 comp) -> chain depth 15 not 60. ----
    if (tid < 360) {
        const int c    = tid % 180;
        const int half = tid / 180;
        const int part = c / 60;
        const int cl   = c - 60 * part;
        const int h = cl / 10, d = cl - 10 * (cl / 10);
        float4 w4[15];
        const float4* wp = reinterpret_cast<const float4*>(qkv_w + c * CH);
        #pragma unroll
        for (int m = 0; m < 15; ++m) w4[m] = wp[m];
        const float bias = qkv_b[c];
        const int t0 = half ? 25 : 0, t1 = half ? NT : 25;
        for (int t = t0; t < t1; ++t) {
            const int tr = t / WSZ, tc = t - WSZ * tr;
            float a = bias;
            if (row0 + tr < IMG && col0 + tc < IMG) {   // wave-uniform-ish skip
                const float4* xr = reinterpret_cast<const float4*>(s_x + t * CH);
                float ax = 0.f, ay = 0.f, az = 0.f, aw = 0.f;
                #pragma unroll
                for (int m = 0; m < 15; ++m) {
                    float4 xv = xr[m];               // broadcast (<=2 addrs per wave)
                    ax = fmaf(xv.x, w4[m].x, ax);
                    ay = fmaf(xv.y, w4[m].y, ay);
                    az = fmaf(xv.z, w4[m].z, az);
                    aw = fmaf(xv.w, w4[m].w, aw);
                }
                a += (ax + ay) + (az + aw);
            }
            if (part == 0)      s_q[(h * NT + t) * 10 + d] = a;
            else if (part == 1) s_k[(h * NT + t) * 12 + d] = a;
            else                s_v[(h * NT + t) * 12 + d] = a;
        }
    }
    __syncthreads();

    // ---- Phase 3: L2-normalize k rows only (q normalized inside P4) ----
    if (tid < 6 * NT) {
        float* p = s_k + tid * 12;
        float s0 = 0.f, s1 = 0.f;
        #pragma unroll
        for (int d = 0; d < 5; ++d) {
            s0 = fmaf(p[2*d],   p[2*d],   s0);
            s1 = fmaf(p[2*d+1], p[2*d+1], s1);
        }
        float inv = 1.f / fmaxf(sqrtf(s0 + s1), 1e-12f);
        #pragma unroll
        for (int d = 0; d < 10; ++d) p[d] *= inv;
    }
    __syncthreads();

    // ---- Phase 4: attention; thread = (head,row); two-pass softmax, a[49]
    //      in AGPRs (all indices static). ----
    if (tid < 6 * NT) {
        const int h = tid / NT, i = tid - h * NT;
        float scale = __expf(fminf(logit_scale[h], LOG100F));
        float q[10];
        {
            const float2* qp = reinterpret_cast<const float2*>(s_q + tid * 10);
            #pragma unroll
            for (int d2 = 0; d2 < 5; ++d2) { float2 t2 = qp[d2]; q[2*d2] = t2.x; q[2*d2+1] = t2.y; }
            float s0 = 0.f, s1 = 0.f;
            #pragma unroll
            for (int d2 = 0; d2 < 5; ++d2) {
                s0 = fmaf(q[2*d2],   q[2*d2],   s0);
                s1 = fmaf(q[2*d2+1], q[2*d2+1], s1);
            }
            float inv = scale / fmaxf(sqrtf(s0 + s1), 1e-12f);  // fold scale into q
            #pragma unroll
            for (int d = 0; d < 10; ++d) q[d] *= inv;
        }
        float a[NT];
        const float4* kb = reinterpret_cast<const float4*>(s_k + h * NT * 12);
        #pragma unroll
        for (int j = 0; j < NT; ++j) {
            float4 k0 = kb[j * 3 + 0];
            float4 k1 = kb[j * 3 + 1];
            float4 k2 = kb[j * 3 + 2];   // .z,.w zeroed pads
            float e0 = q[0]*k0.x + q[2]*k0.z + q[4]*k1.x + q[6]*k1.z + q[8]*k2.x;
            float e1 = q[1]*k0.y + q[3]*k0.w + q[5]*k1.y + q[7]*k1.w + q[9]*k2.y;
            a[j] = e0 + e1;
        }
        float m0 = a[0], m1 = a[1], m2 = a[2], m3 = a[3];
        #pragma unroll
        for (int j = 4; j < 48; j += 4) {
            m0 = fmaxf(m0, a[j]);
            m1 = fmaxf(m1, a[j + 1]);
            m2 = fmaxf(m2, a[j + 2]);
            m3 = fmaxf(m3, a[j + 3]);
        }
        float m = fmaxf(fmaxf(fmaxf(m0, m1), fmaxf(m2, m3)), a[48]);
        float s = 0.f;
        #pragma unroll
        for (int j = 0; j < NT; ++j) { float e = __expf(a[j] - m); a[j] = e; s += e; }
        float o[10];
        #pragma unroll
        for (int d = 0; d < 10; ++d) o[d] = 0.f;
        const float4* vb = reinterpret_cast<const float4*>(s_v + h * NT * 12);
        #pragma unroll
        for (int j = 0; j < NT; ++j) {
            float4 v0 = vb[j * 3 + 0];
            float4 v1 = vb[j * 3 + 1];
            float4 v2 = vb[j * 3 + 2];
            float aj = a[j];
            o[0] += aj * v0.x; o[1] += aj * v0.y; o[2] += aj * v0.z; o[3] += aj * v0.w;
            o[4] += aj * v1.x; o[5] += aj * v1.y; o[6] += aj * v1.z; o[7] += aj * v1.w;
            o[8] += aj * v2.x; o[9] += aj * v2.y;
        }
        float inv = 1.f / s;
        float* op = s_x + i * CH + h * 10;   // s_out aliases s_x
        #pragma unroll
        for (int d2 = 0; d2 < 5; ++d2)
            *reinterpret_cast<float2*>(op + 2 * d2) =
                make_float2(o[2*d2] * inv, o[2*d2+1] * inv);
    }
    __syncthreads();

    // ---- Phase 5: proj. lane<60 = out channel, W-row in regs, tokens over 6 waves ----
    if (lane < 60) {
        float4 w4[15];
        const float4* wp = reinterpret_cast<const float4*>(proj_w + lane * CH);
        #pragma unroll
        for (int m = 0; m < 15; ++m) w4[m] = wp[m];
        const float bias = proj_b[lane];
        for (int t = wv; t < NT; t += 6) {
            int r  = row0 + t / WSZ;
            int cc = col0 + t % WSZ;
            if (r < IMG && cc < IMG) {          // wave-uniform skip
                const float4* xr = reinterpret_cast<const float4*>(s_x + t * CH);
                float ax = 0.f, ay = 0.f, az = 0.f, aw = 0.f;
                #pragma unroll
                for (int m = 0; m < 15; ++m) {
                    float4 xv = xr[m];                    // broadcast
                    ax = fmaf(xv.x, w4[m].x, ax);
                    ay = fmaf(xv.y, w4[m].y, ay);
                    az = fmaf(xv.z, w4[m].z, az);
                    aw = fmaf(xv.w, w4[m].w, aw);
                }
                out[((b * IMG + r) * IMG + cc) * CH + lane] =
                    bias + ((ax + ay) + (az + aw));        // coalesced
            }
        }
    }
}

extern "C" void kernel_launch(void* const* d_in, const int* in_sizes, int n_in,
                              void* d_out, int out_size, void* d_ws, size_t ws_size,
                              hipStream_t stream) {
    hipLaunchKernelGGL(swin_win_attn, dim3(3200), dim3(384), 0, stream,
                       (const float*)d_in[0], (const float*)d_in[1],
                       (const float*)d_in[2], (const float*)d_in[3],
                       (const float*)d_in[4], (const float*)d_in[5],
                       (float*)d_out);
}